// Round 1
// baseline (372.255 us; speedup 1.0000x reference)
//
#include <hip/hip_runtime.h>
#include <math.h>

#define ALPHA 0.1f
#define LAMDA 0.5f
#define D 64

__global__ __launch_bounds__(256) void deg_kernel(
    const int* __restrict__ src, const int* __restrict__ dst,
    float* __restrict__ deg_out, float* __restrict__ deg_in, int E) {
    int e = blockIdx.x * blockDim.x + threadIdx.x;
    if (e < E) {
        atomicAdd(&deg_out[src[e]], 1.0f);
        atomicAdd(&deg_in[dst[e]], 1.0f);
    }
}

__global__ __launch_bounds__(256) void norm_kernel(
    float* __restrict__ deg_out, float* __restrict__ deg_in, int N) {
    int n = blockIdx.x * blockDim.x + threadIdx.x;
    if (n < N) {
        float a = deg_out[n];
        deg_out[n] = (a > 0.0f) ? rsqrtf(a) : 0.0f;
        float b = deg_in[n];
        deg_in[n] = (b > 0.0f) ? rsqrtf(b) : 0.0f;
    }
}

// One 64-lane wave per edge; lane = feature index.
__global__ __launch_bounds__(256) void scatter_kernel(
    const float* __restrict__ x, const int* __restrict__ src,
    const int* __restrict__ dst, const float* __restrict__ norm_src,
    float* __restrict__ agg, int E) {
    int wave = (int)((blockIdx.x * (unsigned)blockDim.x + threadIdx.x) >> 6);
    int lane = threadIdx.x & 63;
    if (wave < E) {
        int s = src[wave];
        int d = dst[wave];
        float ns = norm_src[s];            // broadcast scalar load
        float v = x[(size_t)s * D + lane] * ns;
        atomicAdd(&agg[(size_t)d * D + lane], v);
    }
}

// Block = 256 threads = 4 rows x 64 cols. W cached in LDS.
// agg lives in `out`; read row -> LDS, then overwrite with final output.
__global__ __launch_bounds__(256) void epilogue_kernel(
    const float* __restrict__ x, const float* __restrict__ h0,
    const float* __restrict__ W, const float* __restrict__ norm_dst,
    const int* __restrict__ lptr, float* __restrict__ out, int N) {
    __shared__ float Wl[D][D];          // [k][j], j stride 1 -> conflict-free
    __shared__ float s_row[4][D];       // support rows, broadcast reads

    int t = threadIdx.x;
    for (int i = t; i < D * D; i += 256) Wl[i >> 6][i & 63] = W[i];

    float theta = logf(LAMDA / (float)lptr[0] + 1.0f);

    int r = t >> 6;        // row within block, 0..3
    int j = t & 63;        // column / feature
    int n = blockIdx.x * 4 + r;

    float sup = 0.0f;
    if (n < N) {
        float nd = norm_dst[n];
        size_t base = (size_t)n * D;
        sup = (1.0f - ALPHA) * out[base + j] * nd + ALPHA * h0[base + j];
        s_row[r][j] = sup;
    }
    __syncthreads();

    if (n < N) {
        float acc = 0.0f;
        #pragma unroll
        for (int k = 0; k < D; ++k)
            acc = fmaf(s_row[r][k], Wl[k][j], acc);
        size_t base = (size_t)n * D;
        out[base + j] = theta * acc + (1.0f - theta) * sup + x[base + j];
    }
}

extern "C" void kernel_launch(void* const* d_in, const int* in_sizes, int n_in,
                              void* d_out, int out_size, void* d_ws, size_t ws_size,
                              hipStream_t stream) {
    const float* x   = (const float*)d_in[0];
    const float* h0  = (const float*)d_in[1];
    const int*   src = (const int*)d_in[2];
    const int*   dst = (const int*)d_in[3];
    const float* W   = (const float*)d_in[4];
    const int*   l   = (const int*)d_in[5];

    int N = in_sizes[0] / D;
    int E = in_sizes[2];
    float* out = (float*)d_out;

    float* deg_out = (float*)d_ws;      // N floats
    float* deg_in  = deg_out + N;       // N floats

    hipMemsetAsync(d_ws, 0, 2 * (size_t)N * sizeof(float), stream);
    hipMemsetAsync(d_out, 0, (size_t)N * D * sizeof(float), stream);

    deg_kernel<<<(E + 255) / 256, 256, 0, stream>>>(src, dst, deg_out, deg_in, E);
    norm_kernel<<<(N + 255) / 256, 256, 0, stream>>>(deg_out, deg_in, N);

    // one wave per edge -> E*64 threads
    long long threads = (long long)E * 64;
    int blocks = (int)((threads + 255) / 256);
    scatter_kernel<<<blocks, 256, 0, stream>>>(x, src, dst, deg_out, out, E);

    epilogue_kernel<<<(N + 3) / 4, 256, 0, stream>>>(x, h0, W, deg_in, l, out, N);
}

// Round 2
// 351.089 us; speedup vs baseline: 1.0603x; 1.0603x over previous
//
#include <hip/hip_runtime.h>
#include <math.h>

#define ALPHA 0.1f
#define LAMDA 0.5f
#define D 64

// ---------------- degree histogram (int atomics) ----------------
__global__ __launch_bounds__(256) void deg_kernel(
    const int* __restrict__ src, const int* __restrict__ dst,
    int* __restrict__ deg_out, int* __restrict__ deg_in, int E) {
    int e = blockIdx.x * blockDim.x + threadIdx.x;
    if (e < E) {
        atomicAdd(&deg_out[src[e]], 1);
        atomicAdd(&deg_in[dst[e]], 1);
    }
}

// ---------------- deg -> rsqrt norm factors ----------------
__global__ __launch_bounds__(256) void norm_kernel(
    const int* __restrict__ deg_out, const int* __restrict__ deg_in,
    float* __restrict__ norm_src, float* __restrict__ norm_dst, int N) {
    int n = blockIdx.x * blockDim.x + threadIdx.x;
    if (n < N) {
        int a = deg_out[n];
        norm_src[n] = (a > 0) ? rsqrtf((float)a) : 0.0f;
        int b = deg_in[n];
        norm_dst[n] = (b > 0) ? rsqrtf((float)b) : 0.0f;
    }
}

// ---------------- single-block exclusive scan over deg_in ----------------
__global__ __launch_bounds__(1024) void scan_kernel(
    const int* __restrict__ deg_in, int* __restrict__ row_off, int N, int E) {
    __shared__ int sums[1024];
    int t = threadIdx.x;
    int chunk = (N + 1023) / 1024;
    int beg = t * chunk;
    int end = min(beg + chunk, N);
    int s = 0;
    for (int i = beg; i < end; ++i) s += deg_in[i];
    sums[t] = s;
    __syncthreads();
    // Hillis-Steele inclusive scan over 1024 partials
    for (int off = 1; off < 1024; off <<= 1) {
        int v = (t >= off) ? sums[t - off] : 0;
        __syncthreads();
        sums[t] += v;
        __syncthreads();
    }
    int run = (t == 0) ? 0 : sums[t - 1];
    for (int i = beg; i < end; ++i) {
        row_off[i] = run;
        run += deg_in[i];
    }
    if (t == 1023) row_off[N] = E;
}

// ---------------- bucket edges by dst (stores src id) ----------------
__global__ __launch_bounds__(256) void fill_kernel(
    const int* __restrict__ src, const int* __restrict__ dst,
    const int* __restrict__ row_off, int* __restrict__ cursor,
    int* __restrict__ csr_src, int E) {
    int e = blockIdx.x * blockDim.x + threadIdx.x;
    if (e < E) {
        int d = dst[e];
        int pos = atomicAdd(&cursor[d], 1);
        csr_src[row_off[d] + pos] = src[e];
    }
}

// ---------------- fused gather + GCNII epilogue ----------------
// block = 256 = 4 waves; wave = one dst node; lane = feature j.
__global__ __launch_bounds__(256) void gather_kernel(
    const float* __restrict__ x, const float* __restrict__ h0,
    const float* __restrict__ W, const float* __restrict__ norm_src,
    const float* __restrict__ norm_dst, const int* __restrict__ row_off,
    const int* __restrict__ csr_src, const int* __restrict__ lptr,
    float* __restrict__ out, int N) {
    __shared__ float Wl[D][D];       // [k][j], j contiguous
    __shared__ float s_row[4][D];    // support rows

    int t = threadIdx.x;
    for (int i = t; i < D * D; i += 256) Wl[i >> 6][i & 63] = W[i];

    float theta = logf(LAMDA / (float)lptr[0] + 1.0f);

    int w = t >> 6;     // wave id in block
    int j = t & 63;     // feature / lane
    int n = blockIdx.x * 4 + w;

    float sup = 0.0f;
    if (n < N) {
        int beg = row_off[n];
        int end = row_off[n + 1];
        float acc = 0.0f;
        for (int base = beg; base < end; base += 64) {
            int cnt = min(64, end - base);
            // coalesced edge-id load, one per 64 edges
            int my = (base + j < end) ? csr_src[base + j] : 0;
            for (int i = 0; i < cnt; ++i) {
                int s = __shfl(my, i);
                acc = fmaf(x[(size_t)s * D + j], norm_src[s], acc);
            }
        }
        float hi = acc * norm_dst[n];
        sup = (1.0f - ALPHA) * hi + ALPHA * h0[(size_t)n * D + j];
        s_row[w][j] = sup;
    }
    __syncthreads();

    if (n < N) {
        float accd = 0.0f;
        #pragma unroll
        for (int k = 0; k < D; ++k)
            accd = fmaf(s_row[w][k], Wl[k][j], accd);
        size_t base = (size_t)n * D;
        out[base + j] = theta * accd + (1.0f - theta) * sup + x[base + j];
    }
}

extern "C" void kernel_launch(void* const* d_in, const int* in_sizes, int n_in,
                              void* d_out, int out_size, void* d_ws, size_t ws_size,
                              hipStream_t stream) {
    const float* x   = (const float*)d_in[0];
    const float* h0  = (const float*)d_in[1];
    const int*   src = (const int*)d_in[2];
    const int*   dst = (const int*)d_in[3];
    const float* W   = (const float*)d_in[4];
    const int*   l   = (const int*)d_in[5];

    int N = in_sizes[0] / D;
    int E = in_sizes[2];
    float* out = (float*)d_out;

    // ws layout
    int*   deg_out  = (int*)d_ws;              // N
    int*   deg_in   = deg_out + N;             // N
    int*   row_off  = deg_in + N;              // N+1
    int*   cursor   = row_off + N + 1;         // N
    float* norm_src = (float*)(cursor + N);    // N
    float* norm_dst = norm_src + N;            // N
    int*   csr_src  = (int*)(norm_dst + N);    // E

    hipMemsetAsync(deg_out, 0, 2 * (size_t)N * sizeof(int), stream);
    hipMemsetAsync(cursor, 0, (size_t)N * sizeof(int), stream);

    deg_kernel<<<(E + 255) / 256, 256, 0, stream>>>(src, dst, deg_out, deg_in, E);
    norm_kernel<<<(N + 255) / 256, 256, 0, stream>>>(deg_out, deg_in, norm_src, norm_dst, N);
    scan_kernel<<<1, 1024, 0, stream>>>(deg_in, row_off, N, E);
    fill_kernel<<<(E + 255) / 256, 256, 0, stream>>>(src, dst, row_off, cursor, csr_src, E);
    gather_kernel<<<(N + 3) / 4, 256, 0, stream>>>(x, h0, W, norm_src, norm_dst,
                                                   row_off, csr_src, l, out, N);
}

// Round 3
// 264.281 us; speedup vs baseline: 1.4086x; 1.3285x over previous
//
#include <hip/hip_runtime.h>
#include <math.h>

#define ALPHA 0.1f
#define LAMDA 0.5f
#define D 64

// ---------------- degree histogram (int atomics) ----------------
__global__ __launch_bounds__(256) void deg_kernel(
    const int* __restrict__ src, const int* __restrict__ dst,
    int* __restrict__ deg_out, int* __restrict__ deg_in, int E) {
    int e = blockIdx.x * blockDim.x + threadIdx.x;
    if (e < E) {
        atomicAdd(&deg_out[src[e]], 1);
        atomicAdd(&deg_in[dst[e]], 1);
    }
}

// ---------------- norms + per-block partial sums of deg_in ----------------
// 256 threads, elem i = blockIdx*256 + t. Also reduces deg_in chunk -> blockSums.
__global__ __launch_bounds__(256) void norm_scanA_kernel(
    const int* __restrict__ deg_out, const int* __restrict__ deg_in,
    float* __restrict__ norm_src, float* __restrict__ norm_dst,
    int* __restrict__ blockSums, int N) {
    __shared__ int red[256];
    int t = threadIdx.x;
    int i = blockIdx.x * 256 + t;
    int v = 0;
    if (i < N) {
        int a = deg_out[i];
        norm_src[i] = (a > 0) ? rsqrtf((float)a) : 0.0f;
        int b = deg_in[i];
        norm_dst[i] = (b > 0) ? rsqrtf((float)b) : 0.0f;
        v = b;
    }
    red[t] = v;
    __syncthreads();
    for (int off = 128; off > 0; off >>= 1) {
        if (t < off) red[t] += red[t + off];
        __syncthreads();
    }
    if (t == 0) blockSums[blockIdx.x] = red[0];
}

// ---------------- scan of block sums (single small block) ----------------
__global__ __launch_bounds__(256) void scanB_kernel(
    int* __restrict__ blockSums, int* __restrict__ blockOff,
    int* __restrict__ row_off, int NB, int N, int E) {
    __shared__ int s[256];
    int t = threadIdx.x;
    int v = (t < NB) ? blockSums[t] : 0;
    s[t] = v;
    __syncthreads();
    for (int off = 1; off < 256; off <<= 1) {
        int a = (t >= off) ? s[t - off] : 0;
        __syncthreads();
        s[t] += a;
        __syncthreads();
    }
    if (t < NB) blockOff[t] = s[t] - v;   // exclusive
    if (t == 0) row_off[N] = E;
}

// ---------------- block-local exclusive scan -> row_off & cursor ----------------
__global__ __launch_bounds__(256) void scanC_kernel(
    const int* __restrict__ deg_in, const int* __restrict__ blockOff,
    int* __restrict__ row_off, int* __restrict__ cursor, int N) {
    __shared__ int s[256];
    int t = threadIdx.x;
    int i = blockIdx.x * 256 + t;
    int v = (i < N) ? deg_in[i] : 0;
    s[t] = v;
    __syncthreads();
    for (int off = 1; off < 256; off <<= 1) {
        int a = (t >= off) ? s[t - off] : 0;
        __syncthreads();
        s[t] += a;
        __syncthreads();
    }
    if (i < N) {
        int excl = s[t] - v + blockOff[blockIdx.x];
        row_off[i] = excl;
        cursor[i] = excl;
    }
}

// ---------------- bucket edges by dst (cursor pre-seeded with row_off) ----------------
__global__ __launch_bounds__(256) void fill_kernel(
    const int* __restrict__ src, const int* __restrict__ dst,
    int* __restrict__ cursor, int* __restrict__ csr_src, int E) {
    int e = blockIdx.x * blockDim.x + threadIdx.x;
    if (e < E) {
        int pos = atomicAdd(&cursor[dst[e]], 1);
        csr_src[pos] = src[e];
    }
}

// ---------------- fused gather + GCNII epilogue ----------------
// block = 256 = 4 waves; wave = one dst node; lane = feature j.
__global__ __launch_bounds__(256) void gather_kernel(
    const float* __restrict__ x, const float* __restrict__ h0,
    const float* __restrict__ W, const float* __restrict__ norm_src,
    const float* __restrict__ norm_dst, const int* __restrict__ row_off,
    const int* __restrict__ csr_src, const int* __restrict__ lptr,
    float* __restrict__ out, int N) {
    __shared__ float Wl[D][D];       // [k][j], j contiguous
    __shared__ float s_row[4][D];    // support rows

    int t = threadIdx.x;
    for (int i = t; i < D * D; i += 256) Wl[i >> 6][i & 63] = W[i];

    float theta = logf(LAMDA / (float)lptr[0] + 1.0f);

    int w = t >> 6;     // wave id in block
    int j = t & 63;     // feature / lane
    int n = blockIdx.x * 4 + w;

    float sup = 0.0f;
    if (n < N) {
        int beg = row_off[n];
        int end = row_off[n + 1];
        float acc = 0.0f;
        for (int base = beg; base < end; base += 64) {
            int lim = min(64, end - base);
            int my = (base + j < end) ? csr_src[base + j] : 0;
            int i = 0;
            // 8-wide pipelined batches: 16 independent loads in flight
            for (; i + 8 <= lim; i += 8) {
                int s0 = __shfl(my, i + 0), s1 = __shfl(my, i + 1);
                int s2 = __shfl(my, i + 2), s3 = __shfl(my, i + 3);
                int s4 = __shfl(my, i + 4), s5 = __shfl(my, i + 5);
                int s6 = __shfl(my, i + 6), s7 = __shfl(my, i + 7);
                float x0 = x[(size_t)s0 * D + j]; float n0 = norm_src[s0];
                float x1 = x[(size_t)s1 * D + j]; float n1 = norm_src[s1];
                float x2 = x[(size_t)s2 * D + j]; float n2 = norm_src[s2];
                float x3 = x[(size_t)s3 * D + j]; float n3 = norm_src[s3];
                float x4 = x[(size_t)s4 * D + j]; float n4 = norm_src[s4];
                float x5 = x[(size_t)s5 * D + j]; float n5 = norm_src[s5];
                float x6 = x[(size_t)s6 * D + j]; float n6 = norm_src[s6];
                float x7 = x[(size_t)s7 * D + j]; float n7 = norm_src[s7];
                acc = fmaf(x0, n0, acc); acc = fmaf(x1, n1, acc);
                acc = fmaf(x2, n2, acc); acc = fmaf(x3, n3, acc);
                acc = fmaf(x4, n4, acc); acc = fmaf(x5, n5, acc);
                acc = fmaf(x6, n6, acc); acc = fmaf(x7, n7, acc);
            }
            for (; i + 2 <= lim; i += 2) {
                int s0 = __shfl(my, i + 0), s1 = __shfl(my, i + 1);
                float x0 = x[(size_t)s0 * D + j]; float n0 = norm_src[s0];
                float x1 = x[(size_t)s1 * D + j]; float n1 = norm_src[s1];
                acc = fmaf(x0, n0, acc); acc = fmaf(x1, n1, acc);
            }
            for (; i < lim; ++i) {
                int s = __shfl(my, i);
                acc = fmaf(x[(size_t)s * D + j], norm_src[s], acc);
            }
        }
        float hi = acc * norm_dst[n];
        sup = (1.0f - ALPHA) * hi + ALPHA * h0[(size_t)n * D + j];
        s_row[w][j] = sup;
    }
    __syncthreads();

    if (n < N) {
        float accd = 0.0f;
        #pragma unroll
        for (int k = 0; k < D; ++k)
            accd = fmaf(s_row[w][k], Wl[k][j], accd);
        size_t base = (size_t)n * D;
        out[base + j] = theta * accd + (1.0f - theta) * sup + x[base + j];
    }
}

extern "C" void kernel_launch(void* const* d_in, const int* in_sizes, int n_in,
                              void* d_out, int out_size, void* d_ws, size_t ws_size,
                              hipStream_t stream) {
    const float* x   = (const float*)d_in[0];
    const float* h0  = (const float*)d_in[1];
    const int*   src = (const int*)d_in[2];
    const int*   dst = (const int*)d_in[3];
    const float* W   = (const float*)d_in[4];
    const int*   l   = (const int*)d_in[5];

    int N = in_sizes[0] / D;
    int E = in_sizes[2];
    float* out = (float*)d_out;

    int NB = (N + 255) / 256;   // scan blocks

    // ws layout
    int*   deg_out   = (int*)d_ws;                 // N  (memset)
    int*   deg_in    = deg_out + N;                // N  (memset)
    int*   row_off   = deg_in + N;                 // N+1
    int*   cursor    = row_off + N + 1;            // N
    int*   blockSums = cursor + N;                 // NB
    int*   blockOff  = blockSums + NB;             // NB
    float* norm_src  = (float*)(blockOff + NB);    // N
    float* norm_dst  = norm_src + N;               // N
    int*   csr_src   = (int*)(norm_dst + N);       // E

    hipMemsetAsync(deg_out, 0, 2 * (size_t)N * sizeof(int), stream);

    deg_kernel<<<(E + 255) / 256, 256, 0, stream>>>(src, dst, deg_out, deg_in, E);
    norm_scanA_kernel<<<NB, 256, 0, stream>>>(deg_out, deg_in, norm_src, norm_dst,
                                              blockSums, N);
    scanB_kernel<<<1, 256, 0, stream>>>(blockSums, blockOff, row_off, NB, N, E);
    scanC_kernel<<<NB, 256, 0, stream>>>(deg_in, blockOff, row_off, cursor, N);
    fill_kernel<<<(E + 255) / 256, 256, 0, stream>>>(src, dst, cursor, csr_src, E);
    gather_kernel<<<(N + 3) / 4, 256, 0, stream>>>(x, h0, W, norm_src, norm_dst,
                                                   row_off, csr_src, l, out, N);
}